// Round 2
// baseline (91.691 us; speedup 1.0000x reference)
//
#include <hip/hip_runtime.h>
#include <hip/hip_bf16.h>
#include <math.h>

#define NUM_CLASSES 10
#define BATCH 2048
#define DIM 128
#define INV_T 14.285714285714286f   // 1/0.07; TEMPERATURE/BASE_TEMPERATURE = 1
#define NTILE 16                    // 2048/128 row stripes
#define NPAIR 136                   // upper-triangular 128x128 block pairs
#define VSTRIPE 64                  // normalize stripes (32 rows each) per class

typedef __attribute__((ext_vector_type(8))) short bf16x8;   // 8 bf16 = 4 VGPRs
typedef __attribute__((ext_vector_type(4))) float f32x4;    // MFMA accumulator

// Async 16B-per-lane global->LDS. LDS dest = wave-uniform base + lane*16.
__device__ __forceinline__ void load_lds16(const void* g, void* lds) {
    __builtin_amdgcn_global_load_lds(
        (const __attribute__((address_space(1))) unsigned int*)g,
        (__attribute__((address_space(3))) unsigned int*)lds,
        16, 0, 0);
}

// ---------------------------------------------------------------------------
// 1) Row-normalize preds -> bf16 g. Additionally emits:
//    - norm2[cls][row]  = ||g_row||^2 (post-bf16-round, f32)
//    - vpart[cls][st][0][d] = sum over 32-row stripe of g_row[d]      (vAll)
//    - vpart[cls][st][1][d] = sum over stripe of la_row * g_row[d]    (v1)
//    All unique-slot stores: no atomics, no zero-init, poison-safe.
//    Grid: (VSTRIPE, NUM_CLASSES) x 256. Wave handles 8 consecutive rows.
// ---------------------------------------------------------------------------
__global__ __launch_bounds__(256) void normalize_kernel(
    const float* __restrict__ preds, const int* __restrict__ target,
    __hip_bfloat16* __restrict__ g, float* __restrict__ norm2,
    float* __restrict__ vpart, const float* __restrict__ log_vars,
    float* __restrict__ out)
{
    const int cls = blockIdx.y;
    const int st  = blockIdx.x;
    const int t   = threadIdx.x;
    if (st == 0 && cls == 0 && t == 0) {
        float lv = 0.0f;
        for (int i = 0; i < NUM_CLASSES; ++i) lv += log_vars[i];
        out[0] = lv;
    }

    const int wid  = t >> 6;
    const int lane = t & 63;
    const int rbase = st * 32 + wid * 8;

    float aAllx = 0.0f, aAlly = 0.0f, a1x = 0.0f, a1y = 0.0f;
#pragma unroll
    for (int rr = 0; rr < 8; ++rr) {
        const int r = rbase + rr;
        const float2 v =
            ((const float2*)(preds + ((size_t)cls * BATCH + r) * DIM))[lane];
        float ss = v.x * v.x + v.y * v.y;
#pragma unroll
        for (int m = 32; m; m >>= 1) ss += __shfl_xor(ss, m, 64);
        float rn = 1.0f / sqrtf(ss);
        __hip_bfloat162 o;
        o.x = __float2bfloat16(v.x * rn);
        o.y = __float2bfloat16(v.y * rn);
        *(__hip_bfloat162*)(g + ((size_t)cls * BATCH + r) * DIM + lane * 2) = o;

        float gx = __bfloat162float(o.x);
        float gy = __bfloat162float(o.y);
        float nn = gx * gx + gy * gy;
#pragma unroll
        for (int m = 32; m; m >>= 1) nn += __shfl_xor(nn, m, 64);
        if (lane == 0) norm2[cls * BATCH + r] = nn;

        aAllx += gx; aAlly += gy;
        if (target[r] == cls) { a1x += gx; a1y += gy; }
    }

    // combine 4 waves' per-dim partials (lane owns dims lane*2, lane*2+1)
    __shared__ float vv[4][2][DIM];
    vv[wid][0][lane * 2]     = aAllx;
    vv[wid][0][lane * 2 + 1] = aAlly;
    vv[wid][1][lane * 2]     = a1x;
    vv[wid][1][lane * 2 + 1] = a1y;
    __syncthreads();

    const int sel = t >> 7;          // 0 = vAll, 1 = v1
    const int d   = t & 127;
    float s = vv[0][sel][d] + vv[1][sel][d] + vv[2][sel][d] + vv[3][sel][d];
    vpart[(((size_t)cls * VSTRIPE + st) * 2 + sel) * DIM + d] = s;
}

// ---------------------------------------------------------------------------
// 2) MFMA Gram, upper-tri blocks only; denominator path ONLY (the logit-sum
//    path collapsed analytically into kernels 1/3). Async global_load_lds
//    staging, XOR-swizzled layout. Unique-slot partial stores (no atomics).
// ---------------------------------------------------------------------------
__global__ __launch_bounds__(256) void gram_kernel(
    const __hip_bfloat16* __restrict__ g, float* __restrict__ part)
{
    // decode upper-tri pair (by <= bx)
    int p = blockIdx.x;
    int by = 0, rem = NTILE;
    while (p >= rem) { p -= rem; --rem; ++by; }
    const int bx   = by + p;
    const int cls  = blockIdx.y;
    const int row0 = by * 128;
    const int col0 = bx * 128;
    const bool isDiag = (by == bx);
    const ushort* gc = (const ushort*)g + (size_t)cls * BATCH * DIM;

    __shared__ __align__(16) ushort smem[2 * 128 * 128];   // 64 KiB
    ushort* As = smem;
    ushort* Bs = smem + 128 * 128;

    const int t    = threadIdx.x;
    const int wid  = t >> 6;
    const int lane = t & 63;
    const int tx   = lane & 15;         // C/D: col = lane&15
    const int quad = lane >> 4;         // C/D: row = quad*4 + reg
    const int wm   = (wid >> 1) * 64;
    const int wn   = (wid & 1) * 64;

    // ---- async staging: 8 (+8) global_load_lds_dwordx4 per thread ----
    const int lr = lane >> 4;           // row-within-4
    const int lp = lane & 15;           // chunk position 0..15
#pragma unroll
    for (int s = 0; s < 8; ++s) {
        int rb = s * 16 + wid * 4;      // wave-uniform row base
        int r  = rb + lr;
        int c  = lp ^ (r & 15);         // fetch chunk c into position lp
        load_lds16(gc + (size_t)(row0 + r) * DIM + c * 8, &As[rb * 128]);
        if (!isDiag)
            load_lds16(gc + (size_t)(col0 + r) * DIM + c * 8, &Bs[rb * 128]);
    }
    __syncthreads();   // drains vmcnt before LDS reads

    // ---- MFMA main loop: K=128 in 4 slices of 32 ----
    const ushort* BsR = isDiag ? As : Bs;
    f32x4 acc[4][4] = {};
#pragma unroll
    for (int ks = 0; ks < 4; ++ks) {
        bf16x8 af[4], bg[4];
#pragma unroll
        for (int i = 0; i < 4; ++i) {
            int pa = ((ks * 4 + quad) ^ tx) * 8;   // swizzled chunk offset
            af[i] = *(const bf16x8*)&As [(wm + i * 16 + tx) * 128 + pa];
            bg[i] = *(const bf16x8*)&BsR[(wn + i * 16 + tx) * 128 + pa];
        }
#pragma unroll
        for (int i = 0; i < 4; ++i)
#pragma unroll
            for (int j = 0; j < 4; ++j)
                acc[i][j] = __builtin_amdgcn_mfma_f32_16x16x32_bf16(
                    af[i], bg[j], acc[i][j], 0, 0, 0);
    }
    __syncthreads();   // all tile reads done; safe to reuse LDS

    // ---- epilogue: exp + row/col partial sums (denominator only) ----
    float* rbuf = (float*)smem;                    // [wid][64 x17] = 4x1088 f
    float* cbuf = (float*)smem + 4352;             // [wid][64 x5]  = 4x320  f
    float pcol[4] = {};

#pragma unroll
    for (int i = 0; i < 4; ++i) {
        float prow[4] = {};
#pragma unroll
        for (int j = 0; j < 4; ++j) {
            int cg = col0 + wn + j * 16 + tx;
#pragma unroll
            for (int r = 0; r < 4; ++r) {
                int rg = row0 + wm + i * 16 + quad * 4 + r;
                float e = __expf(acc[i][j][r] * INV_T);
                bool dg = isDiag && (cg == rg);
                e = dg ? 0.0f : e;
                prow[r] += e;
                pcol[j] += e;
            }
        }
#pragma unroll
        for (int r = 0; r < 4; ++r)
            rbuf[wid * 1088 + (i * 16 + quad * 4 + r) * 17 + tx] = prow[r];
    }
#pragma unroll
    for (int j = 0; j < 4; ++j)
        cbuf[wid * 320 + (j * 16 + tx) * 5 + quad] = pcol[j];
    __syncthreads();

    if (t < 128) {
        // rows: wids 2*grp, 2*grp+1 share wm = 64*grp
        int rl = t & 63, grp = t >> 6;
        float den = 0.0f;
#pragma unroll
        for (int w = 0; w < 2; ++w) {
            int base = (2 * grp + w) * 1088 + rl * 17;
#pragma unroll
            for (int x = 0; x < 16; ++x) den += rbuf[base + x];
        }
        part[((size_t)(cls * NTILE + bx)) * BATCH + row0 + t] = den;
    } else if (!isDiag) {
        // cols: wids grp, grp+2 share wn = 64*grp
        int u = t - 128;
        int cl = u & 63, grp = u >> 6;
        float den = 0.0f;
#pragma unroll
        for (int w = 0; w < 2; ++w) {
            int base = (grp + 2 * w) * 320 + cl * 5;
#pragma unroll
            for (int q = 0; q < 4; ++q) den += cbuf[base + q];
        }
        part[((size_t)(cls * NTILE + by)) * BATCH + col0 + u] = den;
    }
}

// ---------------------------------------------------------------------------
// 3) Finalize: 80 blocks x 256 threads, one thread per (cls,row).
//    den = sum of 16 unique Gram slots. Logit-sum reconstructed analytically:
//    S_i = INV_T * (g_i . v_{la_i} - ||g_i||^2),  v1/vAll gathered from vpart.
// ---------------------------------------------------------------------------
__global__ __launch_bounds__(256) void final_kernel(
    const float* __restrict__ part, const float* __restrict__ vpart,
    const float* __restrict__ norm2, const __hip_bfloat16* __restrict__ gbf,
    const int* __restrict__ target, const float* __restrict__ log_vars,
    float* __restrict__ out)
{
    __shared__ int cw[4];
    __shared__ float wred[4];
    __shared__ float vsum[256];          // [0..127]=vAll, [128..255]=v1
    const int t   = threadIdx.x;
    const int idx = blockIdx.x * 256 + t;
    const int cls = idx >> 11;            // block-uniform (2048 % 256 == 0)
    const int a   = idx & (BATCH - 1);

    // block-wide count of (target == cls)
    int c = 0;
#pragma unroll
    for (int k = 0; k < 8; ++k) c += (target[t * 8 + k] == cls);
#pragma unroll
    for (int m = 1; m < 64; m <<= 1) c += __shfl_xor(c, m, 64);
    if ((t & 63) == 0) cw[t >> 6] = c;

    // gather v vectors: sum VSTRIPE stripe-partials for this class
    {
        const int sel = t >> 7, d = t & 127;
        float s = 0.0f;
        for (int st = 0; st < VSTRIPE; ++st)
            s += vpart[(((size_t)cls * VSTRIPE + st) * 2 + sel) * DIM + d];
        vsum[sel * 128 + d] = s;
    }
    __syncthreads();
    const int c1 = cw[0] + cw[1] + cw[2] + cw[3];

    const int la = (target[a] == cls);

    // dot(g_a, v_{la})  (v0 = vAll - v1)
    const ushort* gr = (const ushort*)gbf + ((size_t)cls * BATCH + a) * DIM;
    float dot = 0.0f;
#pragma unroll
    for (int k = 0; k < 16; ++k) {
        bf16x8 ch = *(const bf16x8*)(gr + k * 8);
#pragma unroll
        for (int e = 0; e < 8; ++e) {
            int d = k * 8 + e;
            float gv = __uint_as_float(((unsigned)(unsigned short)ch[e]) << 16);
            float vd = la ? vsum[128 + d] : (vsum[d] - vsum[128 + d]);
            dot = fmaf(gv, vd, dot);
        }
    }
    const float sp = INV_T * (dot - norm2[cls * BATCH + a]);

    // denominator from the 16 unique Gram slots
    float den = 0.0f;
#pragma unroll
    for (int s = 0; s < NTILE; ++s)
        den += part[((size_t)(cls * NTILE + s)) * BATCH + a];

    const int cnt = la ? (c1 - 1) : (BATCH - c1 - 1);
    float mlpp = sp / (float)cnt - logf(den);
    float prt = __expf(-log_vars[cls]) * mlpp;
#pragma unroll
    for (int m = 32; m; m >>= 1) prt += __shfl_xor(prt, m, 64);
    if ((t & 63) == 0) wred[t >> 6] = prt;
    __syncthreads();
    if (t == 0)
        atomicAdd(out, -(wred[0] + wred[1] + wred[2] + wred[3]) / (float)BATCH);
}

// ---------------------------------------------------------------------------
extern "C" void kernel_launch(void* const* d_in, const int* in_sizes, int n_in,
                              void* d_out, int out_size, void* d_ws, size_t ws_size,
                              hipStream_t stream)
{
    const float* preds    = (const float*)d_in[0];   // [10,2048,128] f32
    const int*   target   = (const int*)  d_in[1];   // [2048]
    const float* log_vars = (const float*)d_in[2];   // [10]
    float* out = (float*)d_out;

    char* ws = (char*)d_ws;
    __hip_bfloat16* gbf = (__hip_bfloat16*)ws;                 // 5.24 MB
    ws += (size_t)NUM_CLASSES * BATCH * DIM * 2;
    float* part  = (float*)ws;                                 // 10*16*2048 f
    ws += (size_t)NUM_CLASSES * NTILE * BATCH * 4;
    float* vpart = (float*)ws;                                 // 10*64*2*128 f
    ws += (size_t)NUM_CLASSES * VSTRIPE * 2 * DIM * 4;
    float* norm2 = (float*)ws;                                 // 10*2048 f

    normalize_kernel<<<dim3(VSTRIPE, NUM_CLASSES), 256, 0, stream>>>(
        preds, target, gbf, norm2, vpart, log_vars, out);
    gram_kernel<<<dim3(NPAIR, NUM_CLASSES), 256, 0, stream>>>(gbf, part);
    final_kernel<<<NUM_CLASSES * BATCH / 256, 256, 0, stream>>>(
        part, vpart, norm2, gbf, target, log_vars, out);
}

// Round 3
// 86.095 us; speedup vs baseline: 1.0650x; 1.0650x over previous
//
#include <hip/hip_runtime.h>
#include <hip/hip_bf16.h>
#include <math.h>

#define NUM_CLASSES 10
#define BATCH 2048
#define DIM 128
#define INV_T 14.285714285714286f   // 1/0.07; TEMPERATURE/BASE_TEMPERATURE = 1
#define NTILE 16                    // 2048/128 row stripes
#define NPAIR 136                   // upper-triangular 128x128 block pairs

typedef __attribute__((ext_vector_type(8))) short bf16x8;   // 8 bf16 = 4 VGPRs
typedef __attribute__((ext_vector_type(4))) float f32x4;    // MFMA accumulator

// Async 16B-per-lane global->LDS. LDS dest = wave-uniform base + lane*16.
__device__ __forceinline__ void load_lds16(const void* g, void* lds) {
    __builtin_amdgcn_global_load_lds(
        (const __attribute__((address_space(1))) unsigned int*)g,
        (__attribute__((address_space(3))) unsigned int*)lds,
        16, 0, 0);
}

// ---------------------------------------------------------------------------
// 1) Row-normalize preds -> bf16 g. One row per wave, 5120 blocks (max
//    parallelism — round-2's 640-block serial variant regressed). Block 0
//    initializes out[0] = sum(log_vars) (final_kernel atomicAdds onto it).
// ---------------------------------------------------------------------------
__global__ __launch_bounds__(256) void normalize_kernel(
    const float* __restrict__ preds, __hip_bfloat16* __restrict__ g,
    const float* __restrict__ log_vars, float* __restrict__ out)
{
    int b = blockIdx.x;
    int t = threadIdx.x;
    if (b == 0 && t == 0) {
        float lv = 0.0f;
        for (int i = 0; i < NUM_CLASSES; ++i) lv += log_vars[i];
        out[0] = lv;
    }

    int row  = b * 4 + (t >> 6);
    int lane = t & 63;
    const float2* src = (const float2*)(preds + (size_t)row * DIM);
    float2 v = src[lane];
    float ss = v.x * v.x + v.y * v.y;
#pragma unroll
    for (int m = 32; m; m >>= 1) ss += __shfl_xor(ss, m, 64);
    float rn = 1.0f / sqrtf(ss);
    __hip_bfloat162 o;
    o.x = __float2bfloat16(v.x * rn);
    o.y = __float2bfloat16(v.y * rn);
    *(__hip_bfloat162*)(g + (size_t)row * DIM + lane * 2) = o;
}

// ---------------------------------------------------------------------------
// 2) MFMA Gram, upper-tri blocks only. Async global_load_lds staging,
//    XOR-swizzled layout, merged den+sp epilogue (s2 via class-mask —
//    the in-gram path, verified fastest). Unique-slot partial stores
//    (no atomics, no zero-init, poison-safe). NEW vs round-1: the 256
//    needed target entries are staged once into LDS (tgt[]) instead of
//    ~20 per-lane global loads per thread in the epilogue.
// ---------------------------------------------------------------------------
__global__ __launch_bounds__(256) void gram_kernel(
    const __hip_bfloat16* __restrict__ g, const int* __restrict__ target,
    float2* __restrict__ part)
{
    // decode upper-tri pair (by <= bx)
    int p = blockIdx.x;
    int by = 0, rem = NTILE;
    while (p >= rem) { p -= rem; --rem; ++by; }
    const int bx   = by + p;
    const int cls  = blockIdx.y;
    const int row0 = by * 128;
    const int col0 = bx * 128;
    const bool isDiag = (by == bx);
    const ushort* gc = (const ushort*)g + (size_t)cls * BATCH * DIM;

    __shared__ __align__(16) ushort smem[2 * 128 * 128];   // 64 KiB
    __shared__ int tgt[256];          // [0..127]=target[row0..], [128..]=col
    ushort* As = smem;
    ushort* Bs = smem + 128 * 128;

    const int t    = threadIdx.x;
    const int wid  = t >> 6;
    const int lane = t & 63;
    const int tx   = lane & 15;         // C/D: col = lane&15
    const int quad = lane >> 4;         // C/D: row = quad*4 + reg
    const int wm   = (wid >> 1) * 64;
    const int wn   = (wid & 1) * 64;

    // stage target slices (covered by the staging barrier below)
    tgt[t] = (t < 128) ? target[row0 + t] : target[col0 + (t - 128)];

    // ---- async staging: 8 (+8) global_load_lds_dwordx4 per thread ----
    const int lr = lane >> 4;           // row-within-4
    const int lp = lane & 15;           // chunk position 0..15
#pragma unroll
    for (int s = 0; s < 8; ++s) {
        int rb = s * 16 + wid * 4;      // wave-uniform row base
        int r  = rb + lr;
        int c  = lp ^ (r & 15);         // fetch chunk c into position lp
        load_lds16(gc + (size_t)(row0 + r) * DIM + c * 8, &As[rb * 128]);
        if (!isDiag)
            load_lds16(gc + (size_t)(col0 + r) * DIM + c * 8, &Bs[rb * 128]);
    }
    __syncthreads();   // drains vmcnt before LDS reads; tgt[] also visible

    // ---- MFMA main loop: K=128 in 4 slices of 32 ----
    const ushort* BsR = isDiag ? As : Bs;
    f32x4 acc[4][4] = {};
#pragma unroll
    for (int ks = 0; ks < 4; ++ks) {
        bf16x8 af[4], bg[4];
#pragma unroll
        for (int i = 0; i < 4; ++i) {
            int pa = ((ks * 4 + quad) ^ tx) * 8;   // swizzled chunk offset
            af[i] = *(const bf16x8*)&As [(wm + i * 16 + tx) * 128 + pa];
            bg[i] = *(const bf16x8*)&BsR[(wn + i * 16 + tx) * 128 + pa];
        }
#pragma unroll
        for (int i = 0; i < 4; ++i)
#pragma unroll
            for (int j = 0; j < 4; ++j)
                acc[i][j] = __builtin_amdgcn_mfma_f32_16x16x32_bf16(
                    af[i], bg[j], acc[i][j], 0, 0, 0);
    }
    __syncthreads();   // all tile reads done; safe to reuse LDS

    // ---- epilogue: register partials -> LDS transpose -> unique-slot store
    unsigned laMask = 0;
#pragma unroll
    for (int i = 0; i < 4; ++i)
#pragma unroll
        for (int r = 0; r < 4; ++r)
            if (tgt[wm + i * 16 + quad * 4 + r] == cls)
                laMask |= 1u << (i * 4 + r);
    int lb[4];
#pragma unroll
    for (int j = 0; j < 4; ++j) lb[j] = (tgt[128 + wn + j * 16 + tx] == cls);

    float2* rbuf = (float2*)smem;                    // [wid][64 x17][tx] 34816 B
    float2* cbuf = (float2*)(smem + 17408);          // [wid][64 x5][quad] 10240 B
    float2 pcol[4] = {};

#pragma unroll
    for (int i = 0; i < 4; ++i) {
        float2 prow[4] = {};
#pragma unroll
        for (int j = 0; j < 4; ++j) {
            int cg = col0 + wn + j * 16 + tx;
            int lbj = lb[j];
#pragma unroll
            for (int r = 0; r < 4; ++r) {
                int rg = row0 + wm + i * 16 + quad * 4 + r;
                float logit = acc[i][j][r] * INV_T;
                float e = __expf(logit);
                bool dg = isDiag && (cg == rg);
                e = dg ? 0.0f : e;
                bool same = (((laMask >> (i * 4 + r)) & 1) == (unsigned)lbj) && !dg;
                float sl = same ? logit : 0.0f;
                prow[r].x += e; prow[r].y += sl;
                pcol[j].x += e; pcol[j].y += sl;
            }
        }
#pragma unroll
        for (int r = 0; r < 4; ++r)
            rbuf[wid * 1088 + (i * 16 + quad * 4 + r) * 17 + tx] = prow[r];
    }
#pragma unroll
    for (int j = 0; j < 4; ++j)
        cbuf[wid * 320 + (j * 16 + tx) * 5 + quad] = pcol[j];
    __syncthreads();

    if (t < 128) {
        // rows: wids 2*grp, 2*grp+1 share wm = 64*grp
        int rl = t & 63, grp = t >> 6;
        float den = 0.0f, sp = 0.0f;
#pragma unroll
        for (int w = 0; w < 2; ++w) {
            int base = (2 * grp + w) * 1088 + rl * 17;
#pragma unroll
            for (int x = 0; x < 16; ++x) {
                float2 v = rbuf[base + x];
                den += v.x; sp += v.y;
            }
        }
        part[((size_t)(cls * NTILE + bx)) * BATCH + row0 + t] = make_float2(den, sp);
    } else if (!isDiag) {
        // cols: wids grp, grp+2 share wn = 64*grp
        int u = t - 128;
        int cl = u & 63, grp = u >> 6;
        float den = 0.0f, sp = 0.0f;
#pragma unroll
        for (int w = 0; w < 2; ++w) {
            int base = (grp + 2 * w) * 320 + cl * 5;
#pragma unroll
            for (int q = 0; q < 4; ++q) {
                float2 v = cbuf[base + q];
                den += v.x; sp += v.y;
            }
        }
        part[((size_t)(cls * NTILE + by)) * BATCH + col0 + u] = make_float2(den, sp);
    }
}

// ---------------------------------------------------------------------------
// 3) Finalize: 80 blocks x 256 threads, one thread per (cls,row).
//    Sums the 16 unique-slot partials, recomputes class count from target,
//    accumulates into out via device atomicAdd (out pre-set to sum(log_vars)).
// ---------------------------------------------------------------------------
__global__ __launch_bounds__(256) void final_kernel(
    const float2* __restrict__ part, const int* __restrict__ target,
    const float* __restrict__ log_vars, float* __restrict__ out)
{
    __shared__ int cw[4];
    __shared__ float wred[4];
    const int t   = threadIdx.x;
    const int idx = blockIdx.x * 256 + t;
    const int cls = idx >> 11;            // block-uniform (2048 % 256 == 0)
    const int a   = idx & (BATCH - 1);

    // block-wide count of (target == cls)
    int c = 0;
#pragma unroll
    for (int k = 0; k < 8; ++k) c += (target[t * 8 + k] == cls);
#pragma unroll
    for (int m = 1; m < 64; m <<= 1) c += __shfl_xor(c, m, 64);
    if ((t & 63) == 0) cw[t >> 6] = c;
    __syncthreads();
    const int c1 = cw[0] + cw[1] + cw[2] + cw[3];

    // sum the 16 slot partials for this (cls,row)
    float den = 0.0f, sp = 0.0f;
#pragma unroll
    for (int s = 0; s < NTILE; ++s) {
        float2 v = part[((size_t)(cls * NTILE + s)) * BATCH + a];
        den += v.x; sp += v.y;
    }

    const int la  = (target[a] == cls);
    const int cnt = la ? (c1 - 1) : (BATCH - c1 - 1);
    float mlpp = sp / (float)cnt - logf(den);
    float prt = __expf(-log_vars[cls]) * mlpp;
#pragma unroll
    for (int m = 32; m; m >>= 1) prt += __shfl_xor(prt, m, 64);
    if ((t & 63) == 0) wred[t >> 6] = prt;
    __syncthreads();
    if (t == 0)
        atomicAdd(out, -(wred[0] + wred[1] + wred[2] + wred[3]) / (float)BATCH);
}

// ---------------------------------------------------------------------------
extern "C" void kernel_launch(void* const* d_in, const int* in_sizes, int n_in,
                              void* d_out, int out_size, void* d_ws, size_t ws_size,
                              hipStream_t stream)
{
    const float* preds    = (const float*)d_in[0];   // [10,2048,128] f32
    const int*   target   = (const int*)  d_in[1];   // [2048]
    const float* log_vars = (const float*)d_in[2];   // [10]
    float* out = (float*)d_out;

    __hip_bfloat16* gbf = (__hip_bfloat16*)d_ws;              // 10*2048*128 bf16
    float2* part = (float2*)((char*)d_ws +
                             (size_t)NUM_CLASSES * BATCH * DIM * 2);  // 10*16*2048 float2

    normalize_kernel<<<NUM_CLASSES * BATCH / 4, 256, 0, stream>>>(
        preds, gbf, log_vars, out);
    gram_kernel<<<dim3(NPAIR, NUM_CLASSES), 256, 0, stream>>>(gbf, target, part);
    final_kernel<<<NUM_CLASSES * BATCH / 256, 256, 0, stream>>>(
        part, target, log_vars, out);
}